// Round 8
// baseline (725.102 us; speedup 1.0000x reference)
//
#include <hip/hip_runtime.h>

// ---------------------------------------------------------------------------
// SelfAttentionDecoder: out = (softmax(mask((qWq^T+bq)(xWk^T+bk)^T/8)) (xWv^T+bv)) Wo^T + bo
// B=16, N1=N2=1024, D=1024, H=16, DH=64.
// Round 12: REVERT R11's fp32-A reg-staging (coalescing collapse, 131->345us;
// gll 8-lanes/128B-line vs reg-stage 64 lines/instr). Back to R10 structure:
// bf16 cvt pre-pass + gll-staged gemm_qkv (131us) + gemm_o. Changes vs R10:
//  (1) attn __launch_bounds__(256,5): LDS 32KB x 5 = 160KB exactly, 20
//      waves/CU (was 12) — attn is latency-bound, TLP covers the per-chunk
//      staging drain. VGPR 72 < 102 cap, no spill.
//  (2) prep fused: q/x bf16 cvt + 4x weight cvt + adj pack in ONE dispatch.
// ---------------------------------------------------------------------------

typedef float f32x4 __attribute__((ext_vector_type(4)));
typedef float f32x16 __attribute__((ext_vector_type(16)));
typedef __bf16 bf16x8 __attribute__((ext_vector_type(8)));

// 0.125 * log2(e): QK^T scores arrive pre-scaled for exp2-based softmax.
#define QSCALE 0.18033688f

__device__ __forceinline__ unsigned short f2bf(float f) {
    unsigned u = __builtin_bit_cast(unsigned, f);
    unsigned r = u + 0x7fffu + ((u >> 16) & 1u);   // RNE
    return (unsigned short)(r >> 16);
}
__device__ __forceinline__ unsigned pk2(float a, float b) {
    return (unsigned)f2bf(a) | ((unsigned)f2bf(b) << 16);
}

// ---------------------------------------------------------------------------
// prep: fused fp32->bf16 cvt of q/x (16384 blocks), 4 weights (2048 blocks),
// and adj bitmask pack (128 blocks). Grid 18560.
// ---------------------------------------------------------------------------
__global__ __launch_bounds__(256) void prep(const float* __restrict__ q,
                                            unsigned short* __restrict__ qb,
                                            const float* __restrict__ x,
                                            unsigned short* __restrict__ xb,
                                            const float* __restrict__ W0,
                                            const float* __restrict__ W1,
                                            const float* __restrict__ W2,
                                            const float* __restrict__ W3,
                                            unsigned short* __restrict__ o0,
                                            unsigned short* __restrict__ o1,
                                            unsigned short* __restrict__ o2,
                                            unsigned short* __restrict__ o3,
                                            const int* __restrict__ adj,
                                            unsigned* __restrict__ adjm) {
    const int bid = blockIdx.x;
    if (bid < 16384) {                       // q / x conversion
        const float* s = (bid < 8192) ? q : x;
        unsigned short* d = (bid < 8192) ? qb : xb;
        const int idx = (bid & 8191) * 256 + threadIdx.x;   // 2M chunks of 8
        float4 a = ((const float4*)s)[idx * 2];
        float4 b = ((const float4*)s)[idx * 2 + 1];
        uint4 u;
        u.x = pk2(a.x, a.y); u.y = pk2(a.z, a.w);
        u.z = pk2(b.x, b.y); u.w = pk2(b.z, b.w);
        ((uint4*)d)[idx] = u;
    } else if (bid < 18432) {                // weight conversion
        const int wsel = (bid - 16384) >> 9;
        const float* s = (wsel == 0) ? W0 : (wsel == 1) ? W1 : (wsel == 2) ? W2 : W3;
        unsigned short* d = (wsel == 0) ? o0 : (wsel == 1) ? o1 : (wsel == 2) ? o2 : o3;
        const int idx = ((bid - 16384) & 511) * 256 + threadIdx.x;
        float4 a = ((const float4*)s)[idx * 2];
        float4 b = ((const float4*)s)[idx * 2 + 1];
        uint4 u;
        u.x = pk2(a.x, a.y); u.y = pk2(a.z, a.w);
        u.z = pk2(b.x, b.y); u.w = pk2(b.z, b.w);
        ((uint4*)d)[idx] = u;
    } else {                                 // adj pack
        const int idx = (bid - 18432) * 256 + threadIdx.x;  // 0..32767
        const int* src = adj + (size_t)idx * 32;
        unsigned w = 0;
#pragma unroll
        for (int i = 0; i < 32; i++) w |= (src[i] != 0 ? 1u : 0u) << i;
        adjm[idx] = w;
    }
}

// ---------------------------------------------------------------------------
// Shared GEMM body (R8/R10 structure): 128x128 tile, BK=64 double-buffered,
// 256 thr (4 waves 2x2), gll-16B XOR-swizzled staging, XCD map (8 n-blocks
// of an m-panel share one XCD). OUTM: 0 bf16 row-major, 1 fp32, 2 bf16 V^T.
// ---------------------------------------------------------------------------
template <int OUTM_CONST>  // -1 = runtime outm
__device__ __forceinline__ void gemm_body(const unsigned short* __restrict__ A,
                                          const unsigned short* __restrict__ W,
                                          const float* __restrict__ bias,
                                          void* __restrict__ Cp,
                                          float scale, int b2, int outm_rt) {
    constexpr int N = 1024, K = 1024;
    __shared__ unsigned short As[2][128 * 64];
    __shared__ unsigned short Bs[2][128 * 64];

    const int t    = threadIdx.x;
    const int wave = t >> 6;
    const int lane = t & 63;
    const int xcd  = b2 & 7;
    const int jj   = b2 >> 3;                     // 0..127
    const int n0   = (jj & 7) * 128;
    const int m0   = (xcd * 16 + (jj >> 3)) * 128;
    const int wr   = (wave >> 1) * 64;
    const int wc   = (wave & 1) * 64;
    const int lm   = lane & 15;
    const int quad = lane >> 4;

    int aoff[4], boff[4];
#pragma unroll
    for (int i = 0; i < 4; i++) {
        const int slot = wave * 256 + i * 64 + lane;
        const int r = slot >> 3;
        const int csrc = (slot & 7) ^ (r & 7);
        aoff[i] = (m0 + r) * K + csrc * 8;
        boff[i] = (n0 + r) * K + csrc * 8;
    }

    auto STAGE = [&](int cb, int k0) {
#pragma unroll
        for (int i = 0; i < 4; i++) {
            __builtin_amdgcn_global_load_lds(
                (const __attribute__((address_space(1))) unsigned int*)(A + aoff[i] + k0),
                (__attribute__((address_space(3))) unsigned int*)((char*)&As[cb][0] + wave * 4096 + i * 1024),
                16, 0, 0);
            __builtin_amdgcn_global_load_lds(
                (const __attribute__((address_space(1))) unsigned int*)(W + boff[i] + k0),
                (__attribute__((address_space(3))) unsigned int*)((char*)&Bs[cb][0] + wave * 4096 + i * 1024),
                16, 0, 0);
        }
    };

    f32x4 acc[4][4] = {};

    STAGE(0, 0);
    __syncthreads();   // buf0 ready

    int cur = 0;
    for (int k0 = 0; k0 < K; k0 += 64) {
        if (k0 + 64 < K) STAGE(cur ^ 1, k0 + 64);   // prefetch next tile

        bf16x8 af[2][4], bfr[2][4];
#pragma unroll
        for (int ks = 0; ks < 2; ks++)
#pragma unroll
            for (int i = 0; i < 4; i++) {
                const int pos = ((ks * 4 + quad) ^ (lm & 7)) * 16;
                af[ks][i]  = *(const bf16x8*)((const char*)&As[cur][0] + (wr + i * 16 + lm) * 128 + pos);
                bfr[ks][i] = *(const bf16x8*)((const char*)&Bs[cur][0] + (wc + i * 16 + lm) * 128 + pos);
            }
        __builtin_amdgcn_s_setprio(1);
#pragma unroll
        for (int ks = 0; ks < 2; ks++)
#pragma unroll
            for (int i = 0; i < 4; i++)
#pragma unroll
                for (int j = 0; j < 4; j++)
                    acc[i][j] = __builtin_amdgcn_mfma_f32_16x16x32_bf16(af[ks][i], bfr[ks][j],
                                                                        acc[i][j], 0, 0, 0);
        __builtin_amdgcn_s_setprio(0);
        __syncthreads();   // reads done + next stage drained
        cur ^= 1;
    }

    const int outm = (OUTM_CONST >= 0) ? OUTM_CONST : outm_rt;

#pragma unroll
    for (int i = 0; i < 4; i++) {
        const int row = m0 + wr + i * 16 + quad * 4;
#pragma unroll
        for (int j = 0; j < 4; j++) {
            const int col = n0 + wc + j * 16 + lm;
            const float bb = bias[col];
            if (outm == 2) {
                const int bi = row >> 10, n2 = row & 1023;
                const int hh = col >> 6, dh = col & 63;
                uint2 pkd;
                pkd.x = pk2((acc[i][j][0] + bb) * scale, (acc[i][j][1] + bb) * scale);
                pkd.y = pk2((acc[i][j][2] + bb) * scale, (acc[i][j][3] + bb) * scale);
                *(uint2*)&((unsigned short*)Cp)[((size_t)((bi * 16 + hh) * 64 + dh) << 10) + n2] = pkd;
            } else if (outm == 0) {
#pragma unroll
                for (int rr = 0; rr < 4; rr++)
                    ((unsigned short*)Cp)[(size_t)(row + rr) * N + col] =
                        f2bf((acc[i][j][rr] + bb) * scale);
            } else {
#pragma unroll
                for (int rr = 0; rr < 4; rr++)
                    ((float*)Cp)[(size_t)(row + rr) * N + col] = (acc[i][j][rr] + bb) * scale;
            }
        }
    }
}

// Fused Q/K/V projection GEMM: grid 3072, z = bid>>10 selects the GEMM.
__global__ __launch_bounds__(256, 2) void gemm_qkv(const unsigned short* __restrict__ qb,
                                                   const unsigned short* __restrict__ xb,
                                                   const unsigned short* __restrict__ Wqb,
                                                   const unsigned short* __restrict__ Wkb,
                                                   const unsigned short* __restrict__ Wvb,
                                                   const float* __restrict__ bq,
                                                   const float* __restrict__ bk,
                                                   const float* __restrict__ bv,
                                                   unsigned short* __restrict__ Qo,
                                                   unsigned short* __restrict__ Ko,
                                                   unsigned short* __restrict__ Vo) {
    const int bid = blockIdx.x;
    const int z   = bid >> 10;          // 0=Q 1=K 2=V (wave-uniform)
    const int b2  = bid & 1023;
    const unsigned short* A = (z == 0) ? qb : xb;
    const unsigned short* W = (z == 0) ? Wqb : (z == 1) ? Wkb : Wvb;
    const float* bias       = (z == 0) ? bq : (z == 1) ? bk : bv;
    void* Cp                = (z == 0) ? (void*)Qo : (z == 1) ? (void*)Ko : (void*)Vo;
    const float scale       = (z == 0) ? QSCALE : 1.0f;
    gemm_body<-1>(A, W, bias, Cp, scale, b2, (z == 2) ? 2 : 0);
}

// Single GEMM (O-projection, fp32 out): grid 1024.
__global__ __launch_bounds__(256, 2) void gemm_o(const unsigned short* __restrict__ A,
                                                 const unsigned short* __restrict__ W,
                                                 const float* __restrict__ bias,
                                                 void* __restrict__ Cp,
                                                 float scale) {
    gemm_body<1>(A, W, bias, Cp, scale, blockIdx.x, 1);
}

// ---------------------------------------------------------------------------
// Fallback GEMM (fp32 inputs, conversion in staging) — minimal-ws path only.
// ---------------------------------------------------------------------------
template <bool A_BF16, int OUTM>
__global__ __launch_bounds__(256) void gemm_bt(const void* __restrict__ Ap,
                                               const float* __restrict__ Wp,
                                               const float* __restrict__ bias,
                                               void* __restrict__ Cp,
                                               float scale) {
    constexpr int N = 1024, K = 1024;
    __shared__ unsigned short As[128 * 40];
    __shared__ unsigned short Bs[128 * 40];

    const int t    = threadIdx.x;
    const int n0   = blockIdx.x * 128;
    const int m0   = blockIdx.y * 128;
    const int wave = t >> 6;
    const int lane = t & 63;
    const int wr   = (wave >> 1) * 64;
    const int wc   = (wave & 1) * 64;
    const int lm   = lane & 15;
    const int quad = lane >> 4;
    const int kfr  = quad * 8;
    const int srow  = t >> 1;
    const int shalf = (t & 1) * 16;

    f32x4 acc[4][4] = {};

    for (int k0 = 0; k0 < K; k0 += 32) {
        {
            unsigned short* dst = &As[srow * 40 + shalf];
            if constexpr (A_BF16) {
                const unsigned short* pa =
                    (const unsigned short*)Ap + (size_t)(m0 + srow) * K + k0 + shalf;
                *(uint4*)dst       = *(const uint4*)pa;
                *(uint4*)(dst + 8) = *(const uint4*)(pa + 8);
            } else {
                const float* pa = (const float*)Ap + (size_t)(m0 + srow) * K + k0 + shalf;
                float4 f0 = *(const float4*)(pa + 0);
                float4 f1 = *(const float4*)(pa + 4);
                float4 f2 = *(const float4*)(pa + 8);
                float4 f3 = *(const float4*)(pa + 12);
                uint4 u0, u1;
                u0.x = pk2(f0.x, f0.y); u0.y = pk2(f0.z, f0.w);
                u0.z = pk2(f1.x, f1.y); u0.w = pk2(f1.z, f1.w);
                u1.x = pk2(f2.x, f2.y); u1.y = pk2(f2.z, f2.w);
                u1.z = pk2(f3.x, f3.y); u1.w = pk2(f3.z, f3.w);
                *(uint4*)dst       = u0;
                *(uint4*)(dst + 8) = u1;
            }
        }
        {
            const float* pb = Wp + (size_t)(n0 + srow) * K + k0 + shalf;
            float4 f0 = *(const float4*)(pb + 0);
            float4 f1 = *(const float4*)(pb + 4);
            float4 f2 = *(const float4*)(pb + 8);
            float4 f3 = *(const float4*)(pb + 12);
            uint4 u0, u1;
            u0.x = pk2(f0.x, f0.y); u0.y = pk2(f0.z, f0.w);
            u0.z = pk2(f1.x, f1.y); u0.w = pk2(f1.z, f1.w);
            u1.x = pk2(f2.x, f2.y); u1.y = pk2(f2.z, f2.w);
            u1.z = pk2(f3.x, f3.y); u1.w = pk2(f3.z, f3.w);
            unsigned short* dst = &Bs[srow * 40 + shalf];
            *(uint4*)dst       = u0;
            *(uint4*)(dst + 8) = u1;
        }
        __syncthreads();

        bf16x8 af[4], bfr[4];
#pragma unroll
        for (int i = 0; i < 4; i++)
            af[i] = *reinterpret_cast<const bf16x8*>(&As[(wr + i * 16 + lm) * 40 + kfr]);
#pragma unroll
        for (int j = 0; j < 4; j++)
            bfr[j] = *reinterpret_cast<const bf16x8*>(&Bs[(wc + j * 16 + lm) * 40 + kfr]);
#pragma unroll
        for (int i = 0; i < 4; i++)
#pragma unroll
            for (int j = 0; j < 4; j++)
                acc[i][j] = __builtin_amdgcn_mfma_f32_16x16x32_bf16(af[i], bfr[j],
                                                                    acc[i][j], 0, 0, 0);
        __syncthreads();
    }

#pragma unroll
    for (int i = 0; i < 4; i++) {
        const int row = m0 + wr + i * 16 + quad * 4;
#pragma unroll
        for (int j = 0; j < 4; j++) {
            const int col = n0 + wc + j * 16 + lm;
            const float bb = bias[col];
#pragma unroll
            for (int rr = 0; rr < 4; rr++) {
                const float v = (acc[i][j][rr] + bb) * scale;
                const int m = row + rr;
                if constexpr (OUTM == 0) {
                    ((unsigned short*)Cp)[(size_t)m * N + col] = f2bf(v);
                } else if constexpr (OUTM == 1) {
                    ((float*)Cp)[(size_t)m * N + col] = v;
                } else {
                    const int bi = m >> 10, n2 = m & 1023;
                    const int hh = col >> 6, dh = col & 63;
                    ((unsigned short*)Cp)[((size_t)((bi * 16 + hh) * 64 + dh) << 10) + n2] =
                        f2bf(v);
                }
            }
        }
    }
}

// ---------------------------------------------------------------------------
// Pack adj (minimal-ws path only).
// ---------------------------------------------------------------------------
__global__ __launch_bounds__(256) void pack_adj(const int* __restrict__ adj,
                                                unsigned* __restrict__ adjm) {
    const int idx = blockIdx.x * 256 + threadIdx.x;  // 0..32767
    const int* src = adj + (size_t)idx * 32;
    unsigned w = 0;
#pragma unroll
    for (int i = 0; i < 32; i++) w |= (src[i] != 0 ? 1u : 0u) << i;
    adjm[idx] = w;
}

// ---------------------------------------------------------------------------
// MFMA flash attention, 32x32x16 shape, swapped QK^T, in-register softmax.
// 1D grid 2048 (XCD-swizzled), 4 waves x 32 q-rows = 128 q per block.
// R12: __launch_bounds__(256,5) — 5 blocks/CU (LDS 32KB x 5 = 160KB exactly,
// 20 waves/CU) to cover the per-chunk staging drain with TLP.
// ---------------------------------------------------------------------------
__global__ __launch_bounds__(256, 5) void attn_kernel(const unsigned short* __restrict__ Q,
                                                      const unsigned short* __restrict__ K,
                                                      const unsigned short* __restrict__ Vt,
                                                      const unsigned* __restrict__ adjm,
                                                      unsigned short* __restrict__ O) {
    __shared__ unsigned short Kbuf[2][4096];   // [kv 0..63][8-chunk pos 0..7]
    __shared__ unsigned short Vbuf[2][4096];   // [dh 0..63][pos]

    const int t    = threadIdx.x;
    const int wave = t >> 6;
    const int lane = t & 63;
    const int l32  = lane & 31;
    const int hi   = lane >> 5;

    const int bid   = blockIdx.x;
    const int xcd   = bid & 7;
    const int jj    = bid >> 3;               // 0..255
    const int group = xcd * 32 + (jj >> 3);   // 0..255 = b*16+h
    const int q0    = (jj & 7) * 128;
    const int h     = group & 15;
    const int b     = group >> 4;

    const int qrow = q0 + wave * 32 + l32;    // this lane's q row

    int    ldofs[2];
    size_t kofs[2], vofs[2];
#pragma unroll
    for (int i = 0; i < 2; i++) {
        const int slot = i * 256 + t;
        const int r    = slot >> 3;
        const int cs   = (slot & 7) ^ (r & 7);
        ldofs[i] = slot * 16;
        kofs[i]  = (size_t)(b * 1024 + r) * 1024 + h * 64 + cs * 8;   // + j0*1024
        vofs[i]  = ((size_t)((b * 16 + h) * 64 + r) << 10) + cs * 8;  // + j0
    }

    // Q B-frags: aq[s] covers dh = s*16 + hi*8 .. +8 for col q = l32.
    bf16x8 aq[4];
    {
        const unsigned short* qp =
            Q + ((size_t)(b * 1024 + qrow) * 1024 + h * 64 + hi * 8);
#pragma unroll
        for (int s = 0; s < 4; s++)
            aq[s] = __builtin_bit_cast(bf16x8, *(const uint4*)(qp + s * 16));
    }

    bf16x8 bones;
    {
        uint4 u; u.x = 0x3F803F80u; u.y = u.x; u.z = u.x; u.w = u.x;
        bones = __builtin_bit_cast(bf16x8, u);   // all-ones B fragment
    }

    f32x16 of0 = {}, of1 = {}, ol = {};

    auto STAGE = [&](int bi, int c) {
        const size_t j0 = (size_t)c * 64;
#pragma unroll
        for (int i = 0; i < 2; i++) {
            __builtin_amdgcn_global_load_lds(
                (const __attribute__((address_space(1))) unsigned int*)(K + kofs[i] + j0 * 1024),
                (__attribute__((address_space(3))) unsigned int*)((char*)&Kbuf[bi][0] + ldofs[i]),
                16, 0, 0);
            __builtin_amdgcn_global_load_lds(
                (const __attribute__((address_space(1))) unsigned int*)(Vt + vofs[i] + j0),
                (__attribute__((address_space(3))) unsigned int*)((char*)&Vbuf[bi][0] + ldofs[i]),
                16, 0, 0);
        }
    };

    STAGE(0, 0);
    __syncthreads();   // vmcnt(0) drain: buf0 ready

    int bi = 0;
    for (int c = 0; c < 16; ++c) {
        const uint2 mw = *(const uint2*)&adjm[(size_t)qrow * 32 + c * 2];

        if (c < 15) STAGE(bi ^ 1, c + 1);

        // --- QK^T (swapped): sf[f] over dh steps ---
        f32x16 sf[2] = {{}, {}};
        __builtin_amdgcn_s_setprio(1);
#pragma unroll
        for (int f = 0; f < 2; f++)
#pragma unroll
            for (int s = 0; s < 4; s++) {
                const int pos = ((2 * s + hi) ^ (l32 & 7)) * 16;
                const bf16x8 kf =
                    *(const bf16x8*)((const char*)&Kbuf[bi][0] + (f * 32 + l32) * 128 + pos);
                sf[f] = __builtin_amdgcn_mfma_f32_32x32x16_bf16(kf, aq[s], sf[f], 0, 0, 0);
            }
        __builtin_amdgcn_s_setprio(0);

        // --- mask + exp2 + pack to bf16 pairs (in registers) ---
        unsigned d[2][4][2];
#pragma unroll
        for (int f = 0; f < 2; f++) {
            const unsigned wh = ((f == 0) ? mw.x : mw.y) >> (hi * 4);
            float p[16];
#pragma unroll
            for (int r = 0; r < 16; r++) {
                const unsigned bit = (wh >> ((r & 3) + 8 * (r >> 2))) & 1u;
                p[r] = __builtin_amdgcn_exp2f(bit ? sf[f][r] : -1e30f);
            }
#pragma unroll
            for (int a = 0; a < 4; a++)
#pragma unroll
                for (int bb = 0; bb < 2; bb++) {
                    unsigned dd;
                    asm("v_cvt_pk_bf16_f32 %0, %1, %2"
                        : "=v"(dd) : "v"(p[4 * a + 2 * bb]), "v"(p[4 * a + 2 * bb + 1]));
                    d[f][a][bb] = dd;
                }
        }

        // --- redistribute halves: build PV A-frags tA[s] (kv = s*16+hi*8+j) ---
        bf16x8 tA[4];
#pragma unroll
        for (int s = 0; s < 4; s++) {
            const int f = s >> 1, sg = s & 1;
            unsigned A0 = d[f][2 * sg][0], B0 = d[f][2 * sg + 1][0];
            unsigned A1 = d[f][2 * sg][1], B1 = d[f][2 * sg + 1][1];
            asm("v_permlane32_swap_b32 %0, %1" : "+v"(A0), "+v"(B0));
            asm("v_permlane32_swap_b32 %0, %1" : "+v"(A1), "+v"(B1));
            uint4 td; td.x = A0; td.y = A1; td.z = B0; td.w = B1;
            tA[s] = __builtin_bit_cast(bf16x8, td);
        }

        // --- PV + row-sum ---
        __builtin_amdgcn_s_setprio(1);
#pragma unroll
        for (int s = 0; s < 4; s++) {
            const int pos = ((2 * s + hi) ^ (l32 & 7)) * 16;
            const bf16x8 v0 = *(const bf16x8*)((const char*)&Vbuf[bi][0] + l32 * 128 + pos);
            const bf16x8 v1 = *(const bf16x8*)((const char*)&Vbuf[bi][0] + (32 + l32) * 128 + pos);
            of0 = __builtin_amdgcn_mfma_f32_32x32x16_bf16(tA[s], v0, of0, 0, 0, 0);
            of1 = __builtin_amdgcn_mfma_f32_32x32x16_bf16(tA[s], v1, of1, 0, 0, 0);
            ol  = __builtin_amdgcn_mfma_f32_32x32x16_bf16(tA[s], bones, ol, 0, 0, 0);
        }
        __builtin_amdgcn_s_setprio(0);

        __syncthreads();   // drain: next buf staged + all waves done reading bi
        bi ^= 1;
    }

    // --- normalize + store: lane holds q rows crow(r,hi), d = e*32 + l32 ---
#pragma unroll
    for (int r = 0; r < 16; r++) {
        const float iv = 1.0f / ol[r];
        const size_t row = (size_t)(b * 1024 + q0 + wave * 32 +
                                    (r & 3) + 8 * (r >> 2) + 4 * hi);
        unsigned short* op = O + row * 1024 + h * 64 + l32;
        op[0]  = f2bf(of0[r] * iv);
        op[32] = f2bf(of1[r] * iv);
    }
}

// ---------------------------------------------------------------------------
extern "C" void kernel_launch(void* const* d_in, const int* in_sizes, int n_in,
                              void* d_out, int out_size, void* d_ws, size_t ws_size,
                              hipStream_t stream) {
    const float* q  = (const float*)d_in[0];
    const float* x  = (const float*)d_in[1];
    const float* Wq = (const float*)d_in[2];
    const float* bq = (const float*)d_in[3];
    const float* Wk = (const float*)d_in[4];
    const float* bk = (const float*)d_in[5];
    const float* Wv = (const float*)d_in[6];
    const float* bv = (const float*)d_in[7];
    const float* Wo = (const float*)d_in[8];
    const float* bo = (const float*)d_in[9];
    const int* adj  = (const int*)d_in[10];
    float* out = (float*)d_out;

    const size_t MB = 1024 * 1024;
    char* w = (char*)d_ws;

    dim3 tb(256);
    const size_t FULL_WS = 168 * MB + 128 * 1024;

    if (ws_size >= FULL_WS) {
        unsigned short* qb  = (unsigned short*)(w);
        unsigned short* xb  = (unsigned short*)(w + 32 * MB);
        unsigned short* Wqb = (unsigned short*)(w + 64 * MB);
        unsigned short* Wkb = (unsigned short*)(w + 66 * MB);
        unsigned short* Wvb = (unsigned short*)(w + 68 * MB);
        unsigned short* Wob = (unsigned short*)(w + 70 * MB);
        unsigned short* Qb  = (unsigned short*)(w + 72 * MB);
        unsigned short* Kb  = (unsigned short*)(w + 104 * MB);
        unsigned short* Vtb = (unsigned short*)(w + 136 * MB);
        unsigned* adjm      = (unsigned*)(w + 168 * MB);
        unsigned short* Ob  = qb;  // qb dead after fused QKV GEMM

        hipLaunchKernelGGL(prep, dim3(18560), tb, 0, stream,
                           q, qb, x, xb, Wq, Wk, Wv, Wo, Wqb, Wkb, Wvb, Wob, adj, adjm);
        hipLaunchKernelGGL(gemm_qkv, dim3(3072), tb, 0, stream,
                           qb, xb, Wqb, Wkb, Wvb, bq, bk, bv, Qb, Kb, Vtb);
        hipLaunchKernelGGL(attn_kernel, dim3(2048), tb, 0, stream, Qb, Kb, Vtb, adjm, Ob);
        hipLaunchKernelGGL(gemm_o, dim3(1024), tb, 0, stream, Ob, Wob, bo, (void*)out, 1.0f);
    } else {
        // minimal path (134.1 MB): convert in GEMM staging
        unsigned short* Qb  = (unsigned short*)(w);
        unsigned short* Kb  = (unsigned short*)(w + 32 * MB);
        unsigned short* Vtb = (unsigned short*)(w + 64 * MB);
        unsigned short* Ob  = (unsigned short*)(w + 96 * MB);
        unsigned* adjm      = (unsigned*)(w + 128 * MB);

        hipLaunchKernelGGL(pack_adj, dim3(128), tb, 0, stream, adj, adjm);
        hipLaunchKernelGGL((gemm_bt<false, 0>), dim3(8, 128), tb, 0, stream,
                           (const void*)q, Wq, bq, (void*)Qb, QSCALE);
        hipLaunchKernelGGL((gemm_bt<false, 0>), dim3(8, 128), tb, 0, stream,
                           (const void*)x, Wk, bk, (void*)Kb, 1.0f);
        hipLaunchKernelGGL((gemm_bt<false, 2>), dim3(8, 128), tb, 0, stream,
                           (const void*)x, Wv, bv, (void*)Vtb, 1.0f);
        hipLaunchKernelGGL(attn_kernel, dim3(2048), tb, 0, stream, Qb, Kb, Vtb, adjm, Ob);
        hipLaunchKernelGGL((gemm_bt<true, 1>), dim3(8, 128), tb, 0, stream,
                           (const void*)Ob, Wo, bo, (void*)out, 1.0f);
    }
}

// Round 9
// 448.986 us; speedup vs baseline: 1.6150x; 1.6150x over previous
//
#include <hip/hip_runtime.h>

// ---------------------------------------------------------------------------
// SelfAttentionDecoder: out = (softmax(mask((qWq^T+bq)(xWk^T+bk)^T/8)) (xWv^T+bv)) Wo^T + bo
// B=16, N1=N2=1024, D=1024, H=16, DH=64.
// Round 13: recover from R12's VGPR-cliff (bound-5 forced VGPR=48, spilled
// 48 accumulator regs to scratch: FETCH 50->788MB, attn 112->375us).
// attn -> __launch_bounds__(256,4): cap 128 >= 72 used (no codegen change),
// LDS 4x32KB=128<=160KB -> 4 blocks/CU. Keep R12's fused prep (1 dispatch).
// GEMMs unchanged (gll-staged 128x128 dbuf, XCD map, 131us qkv).
// ---------------------------------------------------------------------------

typedef float f32x4 __attribute__((ext_vector_type(4)));
typedef float f32x16 __attribute__((ext_vector_type(16)));
typedef __bf16 bf16x8 __attribute__((ext_vector_type(8)));

// 0.125 * log2(e): QK^T scores arrive pre-scaled for exp2-based softmax.
#define QSCALE 0.18033688f

__device__ __forceinline__ unsigned short f2bf(float f) {
    unsigned u = __builtin_bit_cast(unsigned, f);
    unsigned r = u + 0x7fffu + ((u >> 16) & 1u);   // RNE
    return (unsigned short)(r >> 16);
}
__device__ __forceinline__ unsigned pk2(float a, float b) {
    return (unsigned)f2bf(a) | ((unsigned)f2bf(b) << 16);
}

// ---------------------------------------------------------------------------
// prep: fused fp32->bf16 cvt of q/x (16384 blocks), 4 weights (2048 blocks),
// and adj bitmask pack (128 blocks). Grid 18560.
// ---------------------------------------------------------------------------
__global__ __launch_bounds__(256) void prep(const float* __restrict__ q,
                                            unsigned short* __restrict__ qb,
                                            const float* __restrict__ x,
                                            unsigned short* __restrict__ xb,
                                            const float* __restrict__ W0,
                                            const float* __restrict__ W1,
                                            const float* __restrict__ W2,
                                            const float* __restrict__ W3,
                                            unsigned short* __restrict__ o0,
                                            unsigned short* __restrict__ o1,
                                            unsigned short* __restrict__ o2,
                                            unsigned short* __restrict__ o3,
                                            const int* __restrict__ adj,
                                            unsigned* __restrict__ adjm) {
    const int bid = blockIdx.x;
    if (bid < 16384) {                       // q / x conversion
        const float* s = (bid < 8192) ? q : x;
        unsigned short* d = (bid < 8192) ? qb : xb;
        const int idx = (bid & 8191) * 256 + threadIdx.x;   // 2M chunks of 8
        float4 a = ((const float4*)s)[idx * 2];
        float4 b = ((const float4*)s)[idx * 2 + 1];
        uint4 u;
        u.x = pk2(a.x, a.y); u.y = pk2(a.z, a.w);
        u.z = pk2(b.x, b.y); u.w = pk2(b.z, b.w);
        ((uint4*)d)[idx] = u;
    } else if (bid < 18432) {                // weight conversion
        const int wsel = (bid - 16384) >> 9;
        const float* s = (wsel == 0) ? W0 : (wsel == 1) ? W1 : (wsel == 2) ? W2 : W3;
        unsigned short* d = (wsel == 0) ? o0 : (wsel == 1) ? o1 : (wsel == 2) ? o2 : o3;
        const int idx = ((bid - 16384) & 511) * 256 + threadIdx.x;
        float4 a = ((const float4*)s)[idx * 2];
        float4 b = ((const float4*)s)[idx * 2 + 1];
        uint4 u;
        u.x = pk2(a.x, a.y); u.y = pk2(a.z, a.w);
        u.z = pk2(b.x, b.y); u.w = pk2(b.z, b.w);
        ((uint4*)d)[idx] = u;
    } else {                                 // adj pack
        const int idx = (bid - 18432) * 256 + threadIdx.x;  // 0..32767
        const int* src = adj + (size_t)idx * 32;
        unsigned w = 0;
#pragma unroll
        for (int i = 0; i < 32; i++) w |= (src[i] != 0 ? 1u : 0u) << i;
        adjm[idx] = w;
    }
}

// ---------------------------------------------------------------------------
// Shared GEMM body (R8/R10 structure): 128x128 tile, BK=64 double-buffered,
// 256 thr (4 waves 2x2), gll-16B XOR-swizzled staging, XCD map (8 n-blocks
// of an m-panel share one XCD). OUTM: 0 bf16 row-major, 1 fp32, 2 bf16 V^T.
// ---------------------------------------------------------------------------
template <int OUTM_CONST>  // -1 = runtime outm
__device__ __forceinline__ void gemm_body(const unsigned short* __restrict__ A,
                                          const unsigned short* __restrict__ W,
                                          const float* __restrict__ bias,
                                          void* __restrict__ Cp,
                                          float scale, int b2, int outm_rt) {
    constexpr int N = 1024, K = 1024;
    __shared__ unsigned short As[2][128 * 64];
    __shared__ unsigned short Bs[2][128 * 64];

    const int t    = threadIdx.x;
    const int wave = t >> 6;
    const int lane = t & 63;
    const int xcd  = b2 & 7;
    const int jj   = b2 >> 3;                     // 0..127
    const int n0   = (jj & 7) * 128;
    const int m0   = (xcd * 16 + (jj >> 3)) * 128;
    const int wr   = (wave >> 1) * 64;
    const int wc   = (wave & 1) * 64;
    const int lm   = lane & 15;
    const int quad = lane >> 4;

    int aoff[4], boff[4];
#pragma unroll
    for (int i = 0; i < 4; i++) {
        const int slot = wave * 256 + i * 64 + lane;
        const int r = slot >> 3;
        const int csrc = (slot & 7) ^ (r & 7);
        aoff[i] = (m0 + r) * K + csrc * 8;
        boff[i] = (n0 + r) * K + csrc * 8;
    }

    auto STAGE = [&](int cb, int k0) {
#pragma unroll
        for (int i = 0; i < 4; i++) {
            __builtin_amdgcn_global_load_lds(
                (const __attribute__((address_space(1))) unsigned int*)(A + aoff[i] + k0),
                (__attribute__((address_space(3))) unsigned int*)((char*)&As[cb][0] + wave * 4096 + i * 1024),
                16, 0, 0);
            __builtin_amdgcn_global_load_lds(
                (const __attribute__((address_space(1))) unsigned int*)(W + boff[i] + k0),
                (__attribute__((address_space(3))) unsigned int*)((char*)&Bs[cb][0] + wave * 4096 + i * 1024),
                16, 0, 0);
        }
    };

    f32x4 acc[4][4] = {};

    STAGE(0, 0);
    __syncthreads();   // buf0 ready

    int cur = 0;
    for (int k0 = 0; k0 < K; k0 += 64) {
        if (k0 + 64 < K) STAGE(cur ^ 1, k0 + 64);   // prefetch next tile

        bf16x8 af[2][4], bfr[2][4];
#pragma unroll
        for (int ks = 0; ks < 2; ks++)
#pragma unroll
            for (int i = 0; i < 4; i++) {
                const int pos = ((ks * 4 + quad) ^ (lm & 7)) * 16;
                af[ks][i]  = *(const bf16x8*)((const char*)&As[cur][0] + (wr + i * 16 + lm) * 128 + pos);
                bfr[ks][i] = *(const bf16x8*)((const char*)&Bs[cur][0] + (wc + i * 16 + lm) * 128 + pos);
            }
        __builtin_amdgcn_s_setprio(1);
#pragma unroll
        for (int ks = 0; ks < 2; ks++)
#pragma unroll
            for (int i = 0; i < 4; i++)
#pragma unroll
                for (int j = 0; j < 4; j++)
                    acc[i][j] = __builtin_amdgcn_mfma_f32_16x16x32_bf16(af[ks][i], bfr[ks][j],
                                                                        acc[i][j], 0, 0, 0);
        __builtin_amdgcn_s_setprio(0);
        __syncthreads();   // reads done + next stage drained
        cur ^= 1;
    }

    const int outm = (OUTM_CONST >= 0) ? OUTM_CONST : outm_rt;

#pragma unroll
    for (int i = 0; i < 4; i++) {
        const int row = m0 + wr + i * 16 + quad * 4;
#pragma unroll
        for (int j = 0; j < 4; j++) {
            const int col = n0 + wc + j * 16 + lm;
            const float bb = bias[col];
            if (outm == 2) {
                const int bi = row >> 10, n2 = row & 1023;
                const int hh = col >> 6, dh = col & 63;
                uint2 pkd;
                pkd.x = pk2((acc[i][j][0] + bb) * scale, (acc[i][j][1] + bb) * scale);
                pkd.y = pk2((acc[i][j][2] + bb) * scale, (acc[i][j][3] + bb) * scale);
                *(uint2*)&((unsigned short*)Cp)[((size_t)((bi * 16 + hh) * 64 + dh) << 10) + n2] = pkd;
            } else if (outm == 0) {
#pragma unroll
                for (int rr = 0; rr < 4; rr++)
                    ((unsigned short*)Cp)[(size_t)(row + rr) * N + col] =
                        f2bf((acc[i][j][rr] + bb) * scale);
            } else {
#pragma unroll
                for (int rr = 0; rr < 4; rr++)
                    ((float*)Cp)[(size_t)(row + rr) * N + col] = (acc[i][j][rr] + bb) * scale;
            }
        }
    }
}

// Fused Q/K/V projection GEMM: grid 3072, z = bid>>10 selects the GEMM.
__global__ __launch_bounds__(256, 2) void gemm_qkv(const unsigned short* __restrict__ qb,
                                                   const unsigned short* __restrict__ xb,
                                                   const unsigned short* __restrict__ Wqb,
                                                   const unsigned short* __restrict__ Wkb,
                                                   const unsigned short* __restrict__ Wvb,
                                                   const float* __restrict__ bq,
                                                   const float* __restrict__ bk,
                                                   const float* __restrict__ bv,
                                                   unsigned short* __restrict__ Qo,
                                                   unsigned short* __restrict__ Ko,
                                                   unsigned short* __restrict__ Vo) {
    const int bid = blockIdx.x;
    const int z   = bid >> 10;          // 0=Q 1=K 2=V (wave-uniform)
    const int b2  = bid & 1023;
    const unsigned short* A = (z == 0) ? qb : xb;
    const unsigned short* W = (z == 0) ? Wqb : (z == 1) ? Wkb : Wvb;
    const float* bias       = (z == 0) ? bq : (z == 1) ? bk : bv;
    void* Cp                = (z == 0) ? (void*)Qo : (z == 1) ? (void*)Ko : (void*)Vo;
    const float scale       = (z == 0) ? QSCALE : 1.0f;
    gemm_body<-1>(A, W, bias, Cp, scale, b2, (z == 2) ? 2 : 0);
}

// Single GEMM (O-projection, fp32 out): grid 1024.
__global__ __launch_bounds__(256, 2) void gemm_o(const unsigned short* __restrict__ A,
                                                 const unsigned short* __restrict__ W,
                                                 const float* __restrict__ bias,
                                                 void* __restrict__ Cp,
                                                 float scale) {
    gemm_body<1>(A, W, bias, Cp, scale, blockIdx.x, 1);
}

// ---------------------------------------------------------------------------
// Fallback GEMM (fp32 inputs, conversion in staging) — minimal-ws path only.
// ---------------------------------------------------------------------------
template <bool A_BF16, int OUTM>
__global__ __launch_bounds__(256) void gemm_bt(const void* __restrict__ Ap,
                                               const float* __restrict__ Wp,
                                               const float* __restrict__ bias,
                                               void* __restrict__ Cp,
                                               float scale) {
    constexpr int N = 1024, K = 1024;
    __shared__ unsigned short As[128 * 40];
    __shared__ unsigned short Bs[128 * 40];

    const int t    = threadIdx.x;
    const int n0   = blockIdx.x * 128;
    const int m0   = blockIdx.y * 128;
    const int wave = t >> 6;
    const int lane = t & 63;
    const int wr   = (wave >> 1) * 64;
    const int wc   = (wave & 1) * 64;
    const int lm   = lane & 15;
    const int quad = lane >> 4;
    const int kfr  = quad * 8;
    const int srow  = t >> 1;
    const int shalf = (t & 1) * 16;

    f32x4 acc[4][4] = {};

    for (int k0 = 0; k0 < K; k0 += 32) {
        {
            unsigned short* dst = &As[srow * 40 + shalf];
            if constexpr (A_BF16) {
                const unsigned short* pa =
                    (const unsigned short*)Ap + (size_t)(m0 + srow) * K + k0 + shalf;
                *(uint4*)dst       = *(const uint4*)pa;
                *(uint4*)(dst + 8) = *(const uint4*)(pa + 8);
            } else {
                const float* pa = (const float*)Ap + (size_t)(m0 + srow) * K + k0 + shalf;
                float4 f0 = *(const float4*)(pa + 0);
                float4 f1 = *(const float4*)(pa + 4);
                float4 f2 = *(const float4*)(pa + 8);
                float4 f3 = *(const float4*)(pa + 12);
                uint4 u0, u1;
                u0.x = pk2(f0.x, f0.y); u0.y = pk2(f0.z, f0.w);
                u0.z = pk2(f1.x, f1.y); u0.w = pk2(f1.z, f1.w);
                u1.x = pk2(f2.x, f2.y); u1.y = pk2(f2.z, f2.w);
                u1.z = pk2(f3.x, f3.y); u1.w = pk2(f3.z, f3.w);
                *(uint4*)dst       = u0;
                *(uint4*)(dst + 8) = u1;
            }
        }
        {
            const float* pb = Wp + (size_t)(n0 + srow) * K + k0 + shalf;
            float4 f0 = *(const float4*)(pb + 0);
            float4 f1 = *(const float4*)(pb + 4);
            float4 f2 = *(const float4*)(pb + 8);
            float4 f3 = *(const float4*)(pb + 12);
            uint4 u0, u1;
            u0.x = pk2(f0.x, f0.y); u0.y = pk2(f0.z, f0.w);
            u0.z = pk2(f1.x, f1.y); u0.w = pk2(f1.z, f1.w);
            u1.x = pk2(f2.x, f2.y); u1.y = pk2(f2.z, f2.w);
            u1.z = pk2(f3.x, f3.y); u1.w = pk2(f3.z, f3.w);
            unsigned short* dst = &Bs[srow * 40 + shalf];
            *(uint4*)dst       = u0;
            *(uint4*)(dst + 8) = u1;
        }
        __syncthreads();

        bf16x8 af[4], bfr[4];
#pragma unroll
        for (int i = 0; i < 4; i++)
            af[i] = *reinterpret_cast<const bf16x8*>(&As[(wr + i * 16 + lm) * 40 + kfr]);
#pragma unroll
        for (int j = 0; j < 4; j++)
            bfr[j] = *reinterpret_cast<const bf16x8*>(&Bs[(wc + j * 16 + lm) * 40 + kfr]);
#pragma unroll
        for (int i = 0; i < 4; i++)
#pragma unroll
            for (int j = 0; j < 4; j++)
                acc[i][j] = __builtin_amdgcn_mfma_f32_16x16x32_bf16(af[i], bfr[j],
                                                                    acc[i][j], 0, 0, 0);
        __syncthreads();
    }

#pragma unroll
    for (int i = 0; i < 4; i++) {
        const int row = m0 + wr + i * 16 + quad * 4;
#pragma unroll
        for (int j = 0; j < 4; j++) {
            const int col = n0 + wc + j * 16 + lm;
            const float bb = bias[col];
#pragma unroll
            for (int rr = 0; rr < 4; rr++) {
                const float v = (acc[i][j][rr] + bb) * scale;
                const int m = row + rr;
                if constexpr (OUTM == 0) {
                    ((unsigned short*)Cp)[(size_t)m * N + col] = f2bf(v);
                } else if constexpr (OUTM == 1) {
                    ((float*)Cp)[(size_t)m * N + col] = v;
                } else {
                    const int bi = m >> 10, n2 = m & 1023;
                    const int hh = col >> 6, dh = col & 63;
                    ((unsigned short*)Cp)[((size_t)((bi * 16 + hh) * 64 + dh) << 10) + n2] =
                        f2bf(v);
                }
            }
        }
    }
}

// ---------------------------------------------------------------------------
// Pack adj (minimal-ws path only).
// ---------------------------------------------------------------------------
__global__ __launch_bounds__(256) void pack_adj(const int* __restrict__ adj,
                                                unsigned* __restrict__ adjm) {
    const int idx = blockIdx.x * 256 + threadIdx.x;  // 0..32767
    const int* src = adj + (size_t)idx * 32;
    unsigned w = 0;
#pragma unroll
    for (int i = 0; i < 32; i++) w |= (src[i] != 0 ? 1u : 0u) << i;
    adjm[idx] = w;
}

// ---------------------------------------------------------------------------
// MFMA flash attention, 32x32x16 shape, swapped QK^T, in-register softmax.
// 1D grid 2048 (XCD-swizzled), 4 waves x 32 q-rows = 128 q per block.
// R13: __launch_bounds__(256,4) — VGPR cap 128 >= 72 used (no spill; R12's
// bound-5 capped at 48 and spilled catastrophically), LDS 4x32KB=128<=160KB
// -> 4 blocks/CU.
// ---------------------------------------------------------------------------
__global__ __launch_bounds__(256, 4) void attn_kernel(const unsigned short* __restrict__ Q,
                                                      const unsigned short* __restrict__ K,
                                                      const unsigned short* __restrict__ Vt,
                                                      const unsigned* __restrict__ adjm,
                                                      unsigned short* __restrict__ O) {
    __shared__ unsigned short Kbuf[2][4096];   // [kv 0..63][8-chunk pos 0..7]
    __shared__ unsigned short Vbuf[2][4096];   // [dh 0..63][pos]

    const int t    = threadIdx.x;
    const int wave = t >> 6;
    const int lane = t & 63;
    const int l32  = lane & 31;
    const int hi   = lane >> 5;

    const int bid   = blockIdx.x;
    const int xcd   = bid & 7;
    const int jj    = bid >> 3;               // 0..255
    const int group = xcd * 32 + (jj >> 3);   // 0..255 = b*16+h
    const int q0    = (jj & 7) * 128;
    const int h     = group & 15;
    const int b     = group >> 4;

    const int qrow = q0 + wave * 32 + l32;    // this lane's q row

    int    ldofs[2];
    size_t kofs[2], vofs[2];
#pragma unroll
    for (int i = 0; i < 2; i++) {
        const int slot = i * 256 + t;
        const int r    = slot >> 3;
        const int cs   = (slot & 7) ^ (r & 7);
        ldofs[i] = slot * 16;
        kofs[i]  = (size_t)(b * 1024 + r) * 1024 + h * 64 + cs * 8;   // + j0*1024
        vofs[i]  = ((size_t)((b * 16 + h) * 64 + r) << 10) + cs * 8;  // + j0
    }

    // Q B-frags: aq[s] covers dh = s*16 + hi*8 .. +8 for col q = l32.
    bf16x8 aq[4];
    {
        const unsigned short* qp =
            Q + ((size_t)(b * 1024 + qrow) * 1024 + h * 64 + hi * 8);
#pragma unroll
        for (int s = 0; s < 4; s++)
            aq[s] = __builtin_bit_cast(bf16x8, *(const uint4*)(qp + s * 16));
    }

    bf16x8 bones;
    {
        uint4 u; u.x = 0x3F803F80u; u.y = u.x; u.z = u.x; u.w = u.x;
        bones = __builtin_bit_cast(bf16x8, u);   // all-ones B fragment
    }

    f32x16 of0 = {}, of1 = {}, ol = {};

    auto STAGE = [&](int bi, int c) {
        const size_t j0 = (size_t)c * 64;
#pragma unroll
        for (int i = 0; i < 2; i++) {
            __builtin_amdgcn_global_load_lds(
                (const __attribute__((address_space(1))) unsigned int*)(K + kofs[i] + j0 * 1024),
                (__attribute__((address_space(3))) unsigned int*)((char*)&Kbuf[bi][0] + ldofs[i]),
                16, 0, 0);
            __builtin_amdgcn_global_load_lds(
                (const __attribute__((address_space(1))) unsigned int*)(Vt + vofs[i] + j0),
                (__attribute__((address_space(3))) unsigned int*)((char*)&Vbuf[bi][0] + ldofs[i]),
                16, 0, 0);
        }
    };

    STAGE(0, 0);
    __syncthreads();   // vmcnt(0) drain: buf0 ready

    int bi = 0;
    for (int c = 0; c < 16; ++c) {
        const uint2 mw = *(const uint2*)&adjm[(size_t)qrow * 32 + c * 2];

        if (c < 15) STAGE(bi ^ 1, c + 1);

        // --- QK^T (swapped): sf[f] over dh steps ---
        f32x16 sf[2] = {{}, {}};
        __builtin_amdgcn_s_setprio(1);
#pragma unroll
        for (int f = 0; f < 2; f++)
#pragma unroll
            for (int s = 0; s < 4; s++) {
                const int pos = ((2 * s + hi) ^ (l32 & 7)) * 16;
                const bf16x8 kf =
                    *(const bf16x8*)((const char*)&Kbuf[bi][0] + (f * 32 + l32) * 128 + pos);
                sf[f] = __builtin_amdgcn_mfma_f32_32x32x16_bf16(kf, aq[s], sf[f], 0, 0, 0);
            }
        __builtin_amdgcn_s_setprio(0);

        // --- mask + exp2 + pack to bf16 pairs (in registers) ---
        unsigned d[2][4][2];
#pragma unroll
        for (int f = 0; f < 2; f++) {
            const unsigned wh = ((f == 0) ? mw.x : mw.y) >> (hi * 4);
            float p[16];
#pragma unroll
            for (int r = 0; r < 16; r++) {
                const unsigned bit = (wh >> ((r & 3) + 8 * (r >> 2))) & 1u;
                p[r] = __builtin_amdgcn_exp2f(bit ? sf[f][r] : -1e30f);
            }
#pragma unroll
            for (int a = 0; a < 4; a++)
#pragma unroll
                for (int bb = 0; bb < 2; bb++) {
                    unsigned dd;
                    asm("v_cvt_pk_bf16_f32 %0, %1, %2"
                        : "=v"(dd) : "v"(p[4 * a + 2 * bb]), "v"(p[4 * a + 2 * bb + 1]));
                    d[f][a][bb] = dd;
                }
        }

        // --- redistribute halves: build PV A-frags tA[s] (kv = s*16+hi*8+j) ---
        bf16x8 tA[4];
#pragma unroll
        for (int s = 0; s < 4; s++) {
            const int f = s >> 1, sg = s & 1;
            unsigned A0 = d[f][2 * sg][0], B0 = d[f][2 * sg + 1][0];
            unsigned A1 = d[f][2 * sg][1], B1 = d[f][2 * sg + 1][1];
            asm("v_permlane32_swap_b32 %0, %1" : "+v"(A0), "+v"(B0));
            asm("v_permlane32_swap_b32 %0, %1" : "+v"(A1), "+v"(B1));
            uint4 td; td.x = A0; td.y = A1; td.z = B0; td.w = B1;
            tA[s] = __builtin_bit_cast(bf16x8, td);
        }

        // --- PV + row-sum ---
        __builtin_amdgcn_s_setprio(1);
#pragma unroll
        for (int s = 0; s < 4; s++) {
            const int pos = ((2 * s + hi) ^ (l32 & 7)) * 16;
            const bf16x8 v0 = *(const bf16x8*)((const char*)&Vbuf[bi][0] + l32 * 128 + pos);
            const bf16x8 v1 = *(const bf16x8*)((const char*)&Vbuf[bi][0] + (32 + l32) * 128 + pos);
            of0 = __builtin_amdgcn_mfma_f32_32x32x16_bf16(tA[s], v0, of0, 0, 0, 0);
            of1 = __builtin_amdgcn_mfma_f32_32x32x16_bf16(tA[s], v1, of1, 0, 0, 0);
            ol  = __builtin_amdgcn_mfma_f32_32x32x16_bf16(tA[s], bones, ol, 0, 0, 0);
        }
        __builtin_amdgcn_s_setprio(0);

        __syncthreads();   // drain: next buf staged + all waves done reading bi
        bi ^= 1;
    }

    // --- normalize + store: lane holds q rows crow(r,hi), d = e*32 + l32 ---
#pragma unroll
    for (int r = 0; r < 16; r++) {
        const float iv = 1.0f / ol[r];
        const size_t row = (size_t)(b * 1024 + q0 + wave * 32 +
                                    (r & 3) + 8 * (r >> 2) + 4 * hi);
        unsigned short* op = O + row * 1024 + h * 64 + l32;
        op[0]  = f2bf(of0[r] * iv);
        op[32] = f2bf(of1[r] * iv);
    }
}

// ---------------------------------------------------------------------------
extern "C" void kernel_launch(void* const* d_in, const int* in_sizes, int n_in,
                              void* d_out, int out_size, void* d_ws, size_t ws_size,
                              hipStream_t stream) {
    const float* q  = (const float*)d_in[0];
    const float* x  = (const float*)d_in[1];
    const float* Wq = (const float*)d_in[2];
    const float* bq = (const float*)d_in[3];
    const float* Wk = (const float*)d_in[4];
    const float* bk = (const float*)d_in[5];
    const float* Wv = (const float*)d_in[6];
    const float* bv = (const float*)d_in[7];
    const float* Wo = (const float*)d_in[8];
    const float* bo = (const float*)d_in[9];
    const int* adj  = (const int*)d_in[10];
    float* out = (float*)d_out;

    const size_t MB = 1024 * 1024;
    char* w = (char*)d_ws;

    dim3 tb(256);
    const size_t FULL_WS = 168 * MB + 128 * 1024;

    if (ws_size >= FULL_WS) {
        unsigned short* qb  = (unsigned short*)(w);
        unsigned short* xb  = (unsigned short*)(w + 32 * MB);
        unsigned short* Wqb = (unsigned short*)(w + 64 * MB);
        unsigned short* Wkb = (unsigned short*)(w + 66 * MB);
        unsigned short* Wvb = (unsigned short*)(w + 68 * MB);
        unsigned short* Wob = (unsigned short*)(w + 70 * MB);
        unsigned short* Qb  = (unsigned short*)(w + 72 * MB);
        unsigned short* Kb  = (unsigned short*)(w + 104 * MB);
        unsigned short* Vtb = (unsigned short*)(w + 136 * MB);
        unsigned* adjm      = (unsigned*)(w + 168 * MB);
        unsigned short* Ob  = qb;  // qb dead after fused QKV GEMM

        hipLaunchKernelGGL(prep, dim3(18560), tb, 0, stream,
                           q, qb, x, xb, Wq, Wk, Wv, Wo, Wqb, Wkb, Wvb, Wob, adj, adjm);
        hipLaunchKernelGGL(gemm_qkv, dim3(3072), tb, 0, stream,
                           qb, xb, Wqb, Wkb, Wvb, bq, bk, bv, Qb, Kb, Vtb);
        hipLaunchKernelGGL(attn_kernel, dim3(2048), tb, 0, stream, Qb, Kb, Vtb, adjm, Ob);
        hipLaunchKernelGGL(gemm_o, dim3(1024), tb, 0, stream, Ob, Wob, bo, (void*)out, 1.0f);
    } else {
        // minimal path (134.1 MB): convert in GEMM staging
        unsigned short* Qb  = (unsigned short*)(w);
        unsigned short* Kb  = (unsigned short*)(w + 32 * MB);
        unsigned short* Vtb = (unsigned short*)(w + 64 * MB);
        unsigned short* Ob  = (unsigned short*)(w + 96 * MB);
        unsigned* adjm      = (unsigned*)(w + 128 * MB);

        hipLaunchKernelGGL(pack_adj, dim3(128), tb, 0, stream, adj, adjm);
        hipLaunchKernelGGL((gemm_bt<false, 0>), dim3(8, 128), tb, 0, stream,
                           (const void*)q, Wq, bq, (void*)Qb, QSCALE);
        hipLaunchKernelGGL((gemm_bt<false, 0>), dim3(8, 128), tb, 0, stream,
                           (const void*)x, Wk, bk, (void*)Kb, 1.0f);
        hipLaunchKernelGGL((gemm_bt<false, 2>), dim3(8, 128), tb, 0, stream,
                           (const void*)x, Wv, bv, (void*)Vtb, 1.0f);
        hipLaunchKernelGGL(attn_kernel, dim3(2048), tb, 0, stream, Qb, Kb, Vtb, adjm, Ob);
        hipLaunchKernelGGL((gemm_bt<true, 1>), dim3(8, 128), tb, 0, stream,
                           (const void*)Ob, Wo, bo, (void*)out, 1.0f);
    }
}